// Round 1
// baseline (960.051 us; speedup 1.0000x reference)
//
#include <hip/hip_runtime.h>

// Problem constants
constexpr int BB = 64;     // batch
constexpr int DD = 256;    // channels
constexpr int NN = 256;    // nodes
constexpr int SS = 1024;   // LP*P spatial positions (= F)
constexpr int FF = 1024;   // node feature dim
constexpr int HH = 512;    // hidden

// ---------------------------------------------------------------------------
// GEMM, K-strided X:  C[b][m][s] = sum_k W[k*M+m] * X[b][k*SC+s] + bias[m]
// grid (SC/64, M/64, B), block 256. 64x64 tile, 4x4 per thread.
// ---------------------------------------------------------------------------
template<int K>
__global__ __launch_bounds__(256)
void gemm_colK(const float* __restrict__ X, const float* __restrict__ W,
               const float* __restrict__ bias, float* __restrict__ C,
               int M, int SC) {
    __shared__ float Ws[16][68];
    __shared__ float Xs[16][68];
    const int b   = blockIdx.z;
    const int m0  = blockIdx.y * 64;
    const int s0  = blockIdx.x * 64;
    const int tid = threadIdx.x;
    const int row  = tid >> 4;          // 0..15  (k within chunk for loads)
    const int col4 = (tid & 15) << 2;   // 0..60
    const int tm = tid >> 4;            // 0..15 -> m sub-tile
    const int ts = tid & 15;            // 0..15 -> s sub-tile
    const float* Xb = X + (size_t)b * K * SC;
    float acc[4][4] = {};

    for (int k0 = 0; k0 < K; k0 += 16) {
        float4 wv = *(const float4*)(W  + (size_t)(k0 + row) * M  + m0 + col4);
        float4 xv = *(const float4*)(Xb + (size_t)(k0 + row) * SC + s0 + col4);
        *(float4*)&Ws[row][col4] = wv;
        *(float4*)&Xs[row][col4] = xv;
        __syncthreads();
#pragma unroll
        for (int kk = 0; kk < 16; ++kk) {
            const float4 w = *(const float4*)&Ws[kk][tm << 2];
            const float4 x = *(const float4*)&Xs[kk][ts << 2];
            const float wa[4] = {w.x, w.y, w.z, w.w};
            const float xa[4] = {x.x, x.y, x.z, x.w};
#pragma unroll
            for (int i = 0; i < 4; ++i)
#pragma unroll
                for (int j = 0; j < 4; ++j)
                    acc[i][j] = fmaf(wa[i], xa[j], acc[i][j]);
        }
        __syncthreads();
    }

    const int mbase = m0 + (tm << 2);
    const int sbase = s0 + (ts << 2);
#pragma unroll
    for (int i = 0; i < 4; ++i) {
        const float bv = bias[mbase + i];
        float4 r;
        r.x = acc[i][0] + bv; r.y = acc[i][1] + bv;
        r.z = acc[i][2] + bv; r.w = acc[i][3] + bv;
        *(float4*)(C + ((size_t)b * M + mbase + i) * SC + sbase) = r;
    }
}

// ---------------------------------------------------------------------------
// GEMM, K-contiguous A:  C[b][n][h] = sum_f A[b][n*K+f] * W[f*HC+h] (+add)
// GROUPW: W/add selected by node-group of the row tile; RELU applied after add.
// grid (HC/64, M/64, B), block 256.
// ---------------------------------------------------------------------------
template<int K, bool GROUPW, bool RELU>
__global__ __launch_bounds__(256)
void gemm_rowK(const float* __restrict__ A, const float* __restrict__ Wbase,
               const float* __restrict__ addv, float* __restrict__ C,
               int M, int HC) {
    __shared__ float As[16][68];
    __shared__ float Ws[16][68];
    const int b   = blockIdx.z;
    const int n0  = blockIdx.y * 64;
    const int h0  = blockIdx.x * 64;
    const int tid = threadIdx.x;
    const int wrow = tid >> 4, wcol = (tid & 15) << 2;
    const int an = tid >> 2;            // 0..63
    const int af = (tid & 3) << 2;      // 0,4,8,12
    const int tm = tid >> 4, ts = tid & 15;

    int grp = 0;
    if (GROUPW) grp = (n0 < 128) ? 0 : (n0 < 192 ? 1 : 2);
    const float* W    = GROUPW ? Wbase + (size_t)grp * K * HC : Wbase;
    const float* addp = GROUPW ? addv + ((size_t)grp * BB + b) * HC : addv;
    const float* Ab   = A + ((size_t)b * M + n0) * K;
    float acc[4][4] = {};

    for (int f0 = 0; f0 < K; f0 += 16) {
        float4 wv = *(const float4*)(W  + (size_t)(f0 + wrow) * HC + h0 + wcol);
        float4 av = *(const float4*)(Ab + (size_t)an * K + f0 + af);
        *(float4*)&Ws[wrow][wcol] = wv;
        As[af + 0][an] = av.x;
        As[af + 1][an] = av.y;
        As[af + 2][an] = av.z;
        As[af + 3][an] = av.w;
        __syncthreads();
#pragma unroll
        for (int kk = 0; kk < 16; ++kk) {
            const float4 a = *(const float4*)&As[kk][tm << 2];
            const float4 w = *(const float4*)&Ws[kk][ts << 2];
            const float aa[4] = {a.x, a.y, a.z, a.w};
            const float wa[4] = {w.x, w.y, w.z, w.w};
#pragma unroll
            for (int i = 0; i < 4; ++i)
#pragma unroll
                for (int j = 0; j < 4; ++j)
                    acc[i][j] = fmaf(aa[i], wa[j], acc[i][j]);
        }
        __syncthreads();
    }

    const int nbase = n0 + (tm << 2);
    const int hbase = h0 + (ts << 2);
#pragma unroll
    for (int i = 0; i < 4; ++i) {
        float4 r;
        r.x = acc[i][0] + addp[hbase + 0];
        r.y = acc[i][1] + addp[hbase + 1];
        r.z = acc[i][2] + addp[hbase + 2];
        r.w = acc[i][3] + addp[hbase + 3];
        if (RELU) {
            r.x = fmaxf(r.x, 0.f); r.y = fmaxf(r.y, 0.f);
            r.z = fmaxf(r.z, 0.f); r.w = fmaxf(r.w, 0.f);
        }
        *(float4*)(C + ((size_t)b * M + nbase + i) * HC + hbase) = r;
    }
}

// ---------------------------------------------------------------------------
// mu[t][b][f] = mean over node slice t of h[b][n][f]
// grid (FF/256, 3*BB), block 256
// ---------------------------------------------------------------------------
__global__ void mu_kernel(const float* __restrict__ h, float* __restrict__ mu) {
    const int f  = blockIdx.x * 256 + threadIdx.x;
    const int tb = blockIdx.y;
    const int t  = tb >> 6;
    const int b  = tb & 63;
    const int lo = (t == 0) ? 0 : (t == 1 ? 128 : 192);
    const int cnt = (t == 0) ? 128 : 64;
    const float* hb = h + ((size_t)b * NN + lo) * SS + f;
    float s = 0.f;
    for (int n = 0; n < cnt; ++n) s += hb[(size_t)n * SS];
    mu[((size_t)t * BB + b) * FF + f] = s * (1.0f / cnt);
}

// ---------------------------------------------------------------------------
// Wsum[t] = (1/3) * sum of the 3 Wr matrices whose dst type is t
// grid (FF*HH/256, 3), block 256
// ---------------------------------------------------------------------------
__global__ void wrsum_kernel(const float* __restrict__ Wr, float* __restrict__ Wsum) {
    const int FHsz = FF * HH;
    const int idx = blockIdx.x * 256 + threadIdx.x;
    const int t = blockIdx.y;
    // dst A: edges {1,3,6}; dst B: {0,5,7}; dst C: {2,4,8}
    const int e0[3] = {1, 0, 2}, e1[3] = {3, 5, 4}, e2[3] = {6, 7, 8};
    float s = Wr[(size_t)e0[t] * FHsz + idx] + Wr[(size_t)e1[t] * FHsz + idx] +
              Wr[(size_t)e2[t] * FHsz + idx];
    Wsum[(size_t)t * FHsz + idx] = s * (1.f / 3.f);
}

// ---------------------------------------------------------------------------
// beta[t][b][h] = (1/3) sum_{edges i -> t} ( bl[i][h] + mu[src_i][b] . Wl[i][:,h] )
// grid (3, BB/4), block 512 (one thread per h, 4 batches per thread)
// ---------------------------------------------------------------------------
__global__ __launch_bounds__(512)
void beta_kernel(const float* __restrict__ mu, const float* __restrict__ Wl,
                 const float* __restrict__ bl, float* __restrict__ beta) {
    __shared__ float smu[3][4][128];
    const int t  = blockIdx.x;
    const int b4 = blockIdx.y * 4;
    const int hh = threadIdx.x;
    const int eArr[3][3] = {{1, 3, 6}, {0, 5, 7}, {2, 4, 8}};
    const int sArr[3][3] = {{1, 2, 0}, {0, 2, 1}, {0, 1, 2}};
    float acc[4];
    {
        const float bsum = bl[eArr[t][0] * HH + hh] + bl[eArr[t][1] * HH + hh] +
                           bl[eArr[t][2] * HH + hh];
#pragma unroll
        for (int j = 0; j < 4; ++j) acc[j] = bsum;
    }
    for (int f0 = 0; f0 < FF; f0 += 128) {
        __syncthreads();
        for (int l = threadIdx.x; l < 3 * 4 * 128; l += 512) {
            const int k = l >> 9;
            const int j = (l >> 7) & 3;
            const int f = l & 127;
            smu[k][j][f] = mu[((size_t)sArr[t][k] * BB + b4 + j) * FF + f0 + f];
        }
        __syncthreads();
#pragma unroll
        for (int k = 0; k < 3; ++k) {
            const float* Wp = Wl + ((size_t)eArr[t][k] * FF + f0) * HH + hh;
#pragma unroll 4
            for (int f = 0; f < 128; ++f) {
                const float w = Wp[(size_t)f * HH];
                acc[0] = fmaf(smu[k][0][f], w, acc[0]);
                acc[1] = fmaf(smu[k][1][f], w, acc[1]);
                acc[2] = fmaf(smu[k][2][f], w, acc[2]);
                acc[3] = fmaf(smu[k][3][f], w, acc[3]);
            }
        }
    }
#pragma unroll
    for (int j = 0; j < 4; ++j)
        beta[((size_t)t * BB + b4 + j) * HH + hh] = acc[j] * (1.f / 3.f);
}

// ---------------------------------------------------------------------------
extern "C" void kernel_launch(void* const* d_in, const int* in_sizes, int n_in,
                              void* d_out, int out_size, void* d_ws, size_t ws_size,
                              hipStream_t stream) {
    const float* x  = (const float*)d_in[0];
    const float* W1 = (const float*)d_in[1];
    const float* b1 = (const float*)d_in[2];
    const float* Wl = (const float*)d_in[3];
    const float* bl = (const float*)d_in[4];
    const float* Wr = (const float*)d_in[5];
    const float* Wf = (const float*)d_in[6];
    const float* bf = (const float*)d_in[7];
    const float* W2 = (const float*)d_in[8];
    const float* b2 = (const float*)d_in[9];
    float* y = (float*)d_out;

    // workspace layout (floats)
    float* ws   = (float*)d_ws;
    float* h    = ws;                       // [64][256][1024] = 16,777,216
    float* o    = h + (size_t)16777216;     // [64][256][512]  =  8,388,608
    float* mu   = o + (size_t)8388608;      // [3][64][1024]   =    196,608
    float* beta = mu + (size_t)196608;      // [3][64][512]    =     98,304
    float* wsum = beta + (size_t)98304;     // [3][1024][512]  =  1,572,864
    float* outm = h;                        // alias: h is dead after gemm_rowK #1

    // 1. h = linear1(x): [B,N,S]
    gemm_colK<DD><<<dim3(SS / 64, NN / 64, BB), dim3(256), 0, stream>>>(
        x, W1, b1, h, NN, SS);
    // 2. Wr_sum (independent of h)
    wrsum_kernel<<<dim3(FF * HH / 256, 3), dim3(256), 0, stream>>>(Wr, wsum);
    // 3. mu over node slices
    mu_kernel<<<dim3(FF / 256, 3 * BB), dim3(256), 0, stream>>>(h, mu);
    // 4. beta per (t, b)
    beta_kernel<<<dim3(3, BB / 4), dim3(512), 0, stream>>>(mu, Wl, bl, beta);
    // 5. r = relu(beta + hf @ Wr_sum[t]): [B,N,HID]
    gemm_rowK<FF, true, true><<<dim3(HH / 64, NN / 64, BB), dim3(256), 0, stream>>>(
        h, wsum, beta, o, NN, HH);
    // 6. out = r @ Wf + bf: [B,N,F]   (writes into h's region; h is dead)
    gemm_rowK<HH, false, false><<<dim3(FF / 64, NN / 64, BB), dim3(256), 0, stream>>>(
        o, Wf, bf, outm, NN, FF);
    // 7. y = linear2(out): [B,D,S]
    gemm_colK<NN><<<dim3(SS / 64, DD / 64, BB), dim3(256), 0, stream>>>(
        outm, W2, b2, y, DD, SS);
}

// Round 2
// 361.378 us; speedup vs baseline: 2.6566x; 2.6566x over previous
//
#include <hip/hip_runtime.h>

typedef unsigned short u16;
typedef __attribute__((ext_vector_type(8))) short bf16x8;
typedef __attribute__((ext_vector_type(4))) float f32x4;

// Problem constants
constexpr int BB = 64;     // batch
constexpr int NN = 256;    // nodes (= linear1 out)
constexpr int SS = 1024;   // LP*P spatial (= F)
constexpr int FF = 1024;   // node feature dim
constexpr int HH = 512;    // hidden

// edge bookkeeping: EDGE_TYPES = [AB,BA,AC,CA,BC,CB,AA,BB,CC]
// dst A edges {1,3,6} (src B,C,A); dst B {0,5,7} (src A,C,B); dst C {2,4,8} (src A,B,C)
__device__ const int d_eArr[3][3] = {{1, 3, 6}, {0, 5, 7}, {2, 4, 8}};
// muCat slot: for src type tp, (dst t) -> e' slot with sArr[t][e']==tp
__device__ const int d_slotE[3][3] = {{2, 0, 0}, {0, 2, 1}, {1, 1, 2}};

__device__ __forceinline__ u16 f2bf(float f) {
    union { float f; unsigned u; } v; v.f = f;
    unsigned r = v.u + 0x7FFFu + ((v.u >> 16) & 1u);
    return (u16)(r >> 16);
}
__device__ __forceinline__ float bf2f(u16 h) {
    union { unsigned u; float f; } v; v.u = ((unsigned)h) << 16;
    return v.f;
}
__device__ __forceinline__ int swz(int lin) {            // XOR-swizzle 16B slots by row&7
    return lin ^ (((lin >> 6) & 7) << 4);
}

// ---------------------------------------------------------------------------
// Batched transpose fp32 -> bf16: out[b][c][r] = in[b][r][c]
// grid (C/32, R/32, nbatch), block 256
// ---------------------------------------------------------------------------
__global__ __launch_bounds__(256)
void transpose_bf16(const float* __restrict__ in, u16* __restrict__ out, int R, int C) {
    __shared__ float tile[32][33];
    const int b = blockIdx.z;
    in  += (size_t)b * R * C;
    out += (size_t)b * R * C;
    const int c0 = blockIdx.x * 32, r0 = blockIdx.y * 32;
    const int x = threadIdx.x & 31, y = threadIdx.x >> 5;   // y in 0..7
#pragma unroll
    for (int k = 0; k < 4; ++k)
        tile[y + 8 * k][x] = in[(size_t)(r0 + y + 8 * k) * C + c0 + x];
    __syncthreads();
#pragma unroll
    for (int k = 0; k < 4; ++k)
        out[(size_t)(c0 + y + 8 * k) * R + r0 + x] = f2bf(tile[x][y + 8 * k]);
}

// ---------------------------------------------------------------------------
// WlTcat[t][h][e'*1024+f] = Wl[eArr[t][e']][f][h]  (bf16)
// grid (512/32, 1024/32, 9) block 256
// ---------------------------------------------------------------------------
__global__ __launch_bounds__(256)
void wlt_kernel(const float* __restrict__ Wl, u16* __restrict__ WlTcat) {
    __shared__ float tile[32][33];
    const int p = blockIdx.z, t = p / 3, ep = p % 3;
    const int e = d_eArr[t][ep];
    const int h0 = blockIdx.x * 32, f0 = blockIdx.y * 32;
    const int x = threadIdx.x & 31, y = threadIdx.x >> 5;
    const float* src = Wl + (size_t)e * FF * HH;
#pragma unroll
    for (int k = 0; k < 4; ++k)
        tile[y + 8 * k][x] = src[(size_t)(f0 + y + 8 * k) * HH + h0 + x];
    __syncthreads();
    u16* dst = WlTcat + (size_t)t * HH * 3072 + (size_t)ep * 1024;
#pragma unroll
    for (int k = 0; k < 4; ++k)
        dst[(size_t)(h0 + y + 8 * k) * 3072 + f0 + x] = f2bf(tile[x][y + 8 * k]);
}

// ---------------------------------------------------------------------------
// WsumT[t][h][f] = (1/3) * sum_{e in dst t} Wr[e][f][h]  (bf16)
// grid (512/32, 1024/32, 3) block 256
// ---------------------------------------------------------------------------
__global__ __launch_bounds__(256)
void wrsumT_kernel(const float* __restrict__ Wr, u16* __restrict__ WsumT) {
    __shared__ float tile[32][33];
    const int t = blockIdx.z;
    const int h0 = blockIdx.x * 32, f0 = blockIdx.y * 32;
    const int x = threadIdx.x & 31, y = threadIdx.x >> 5;
    const int e0 = d_eArr[t][0], e1 = d_eArr[t][1], e2 = d_eArr[t][2];
#pragma unroll
    for (int k = 0; k < 4; ++k) {
        const size_t off = (size_t)(f0 + y + 8 * k) * HH + h0 + x;
        float s = Wr[(size_t)e0 * FF * HH + off] + Wr[(size_t)e1 * FF * HH + off] +
                  Wr[(size_t)e2 * FF * HH + off];
        tile[y + 8 * k][x] = s * (1.f / 3.f);
    }
    __syncthreads();
    u16* dst = WsumT + (size_t)t * HH * FF;
#pragma unroll
    for (int k = 0; k < 4; ++k)
        dst[(size_t)(h0 + y + 8 * k) * FF + f0 + x] = f2bf(tile[x][y + 8 * k]);
}

// ---------------------------------------------------------------------------
// mu over node slices (bf16 h in), replicated into muCat[3][64][3072] (bf16)
// grid (4, 192) block 256
// ---------------------------------------------------------------------------
__global__ __launch_bounds__(256)
void mu_kernel(const u16* __restrict__ h, u16* __restrict__ muCat) {
    const int f  = blockIdx.x * 256 + threadIdx.x;
    const int tb = blockIdx.y;
    const int tp = tb >> 6;            // src type
    const int b  = tb & 63;
    const int lo  = (tp == 0) ? 0 : (tp == 1 ? 128 : 192);
    const int cnt = (tp == 0) ? 128 : 64;
    const u16* hb = h + ((size_t)b * NN + lo) * SS + f;
    float s = 0.f;
    for (int n = 0; n < cnt; ++n) s += bf2f(hb[(size_t)n * SS]);
    const u16 v = f2bf(s * (1.0f / cnt));
#pragma unroll
    for (int t = 0; t < 3; ++t) {
        const int ep = d_slotE[tp][t];
        muCat[((size_t)t * BB + b) * 3072 + (size_t)ep * 1024 + f] = v;
    }
}

// ---------------------------------------------------------------------------
// blsum[t][h] = sum_{e in dst t} bl[e][h]   (fp32)
// ---------------------------------------------------------------------------
__global__ void blsum_kernel(const float* __restrict__ bl, float* __restrict__ blsum) {
    const int t = blockIdx.x, hh = threadIdx.x;
    blsum[t * HH + hh] = bl[d_eArr[t][0] * HH + hh] + bl[d_eArr[t][1] * HH + hh] +
                         bl[d_eArr[t][2] * HH + hh];
}

// ---------------------------------------------------------------------------
// MFMA GEMM: C[M][N] = A[M][K] * (Bt[N][K])^T  (+ epilogue)
// A, Bt row-major bf16 (u16). BK=32, 256 threads (4 waves, 2x2 wave grid).
// EPI: 0 = bf16 out, + aux1[row]
//      1 = f32 out, no bias
//      2 = bf16 out, + (aux1[t*64+b][col] + aux2[t][col])/3, relu   (G5)
//      3 = f32 out, + aux1[row]
// GRP: B-operand / aux group t selected by row-tile (G5: 512x1024 per group)
// ---------------------------------------------------------------------------
template<int BM, int BN, int EPI, bool GRP>
__global__ __launch_bounds__(256)
void gemm_mfma(const u16* __restrict__ Abase, const u16* __restrict__ Bbase,
               void* __restrict__ Cbase, const float* __restrict__ aux1,
               const float* __restrict__ aux2,
               int K, int N, long long sA, long long sB, long long sC)
{
    constexpr int BK = 32;
    constexpr int BLK = 256;
    constexpr int WM = BM / 2, WN = BN / 2;
    constexpr int FM = WM / 16, FN = WN / 16;
    constexpr int NIA = (BM * 4) / BLK;       // 16B chunks per thread for A tile
    constexpr int NIB = (BN * 4) / BLK;
    __shared__ __align__(16) unsigned char As[BM * 64];
    __shared__ __align__(16) unsigned char Bs[BN * 64];

    const int b  = blockIdx.z;
    const int n0 = blockIdx.x * BN;
    const int m0 = blockIdx.y * BM;
    int t = 0;
    const u16* A = Abase + (size_t)b * sA + (size_t)m0 * K;
    const u16* Bt;
    if (GRP) {
        t = (m0 >= 192) ? 2 : (m0 >= 128 ? 1 : 0);
        Bt = Bbase + (size_t)t * (HH * FF) + (size_t)n0 * K;
    } else {
        Bt = Bbase + (size_t)b * sB + (size_t)n0 * K;
    }

    const int tid  = threadIdx.x;
    const int lane = tid & 63;
    const int wave = tid >> 6;
    const int wm = wave >> 1, wn = wave & 1;

    // staging: chunk c = i*BLK+tid -> A row c>>2, 16B slot c&3; LDS swizzled
    int stA[NIA], stB[NIB];
    const u16* pAg[NIA];
    const u16* pBg[NIB];
#pragma unroll
    for (int i = 0; i < NIA; ++i) {
        const int c = i * BLK + tid;
        stA[i] = swz(c * 16);
        pAg[i] = A + (size_t)(c >> 2) * K + (c & 3) * 8;
    }
#pragma unroll
    for (int i = 0; i < NIB; ++i) {
        const int c = i * BLK + tid;
        stB[i] = swz(c * 16);
        pBg[i] = Bt + (size_t)(c >> 2) * K + (c & 3) * 8;
    }
    // fragment read addresses (fixed per thread)
    const unsigned char* rdA[FM];
    const unsigned char* rdB[FN];
#pragma unroll
    for (int i = 0; i < FM; ++i)
        rdA[i] = &As[swz((wm * WM + i * 16 + (lane & 15)) * 64 + ((lane >> 4) << 4))];
#pragma unroll
    for (int j = 0; j < FN; ++j)
        rdB[j] = &Bs[swz((wn * WN + j * 16 + (lane & 15)) * 64 + ((lane >> 4) << 4))];

    const f32x4 zero4 = {0.f, 0.f, 0.f, 0.f};
    f32x4 acc[FM][FN];
#pragma unroll
    for (int i = 0; i < FM; ++i)
#pragma unroll
        for (int j = 0; j < FN; ++j) acc[i][j] = zero4;

    int4 pa[NIA], pb[NIB];
#pragma unroll
    for (int i = 0; i < NIA; ++i) pa[i] = *(const int4*)(pAg[i]);
#pragma unroll
    for (int i = 0; i < NIB; ++i) pb[i] = *(const int4*)(pBg[i]);

    for (int k0 = 0; k0 < K; k0 += BK) {
        __syncthreads();          // all readers of previous tile done
#pragma unroll
        for (int i = 0; i < NIA; ++i) *(int4*)&As[stA[i]] = pa[i];
#pragma unroll
        for (int i = 0; i < NIB; ++i) *(int4*)&Bs[stB[i]] = pb[i];
        __syncthreads();          // tile visible
        if (k0 + BK < K) {        // prefetch next tile (overlaps MFMA below)
#pragma unroll
            for (int i = 0; i < NIA; ++i) pa[i] = *(const int4*)(pAg[i] + k0 + BK);
#pragma unroll
            for (int i = 0; i < NIB; ++i) pb[i] = *(const int4*)(pBg[i] + k0 + BK);
        }
        bf16x8 af[FM], bq[FN];
#pragma unroll
        for (int i = 0; i < FM; ++i) af[i] = *(const bf16x8*)rdA[i];
#pragma unroll
        for (int j = 0; j < FN; ++j) bq[j] = *(const bf16x8*)rdB[j];
#pragma unroll
        for (int i = 0; i < FM; ++i)
#pragma unroll
            for (int j = 0; j < FN; ++j)
                acc[i][j] = __builtin_amdgcn_mfma_f32_16x16x32_bf16(af[i], bq[j], acc[i][j], 0, 0, 0);
    }

    // epilogue: C row = rbase + i*16 + (lane>>4)*4 + rr, col = cbase + j*16 + (lane&15)
    const int rbase = m0 + wm * WM;
    const int cbase = n0 + wn * WN;
    if constexpr (EPI == 1 || EPI == 3) {
        float* C = (float*)Cbase + (size_t)b * sC;
#pragma unroll
        for (int i = 0; i < FM; ++i)
#pragma unroll
            for (int rr = 0; rr < 4; ++rr) {
                const int row = rbase + i * 16 + ((lane >> 4) << 2) + rr;
                const float bias = (EPI == 3) ? aux1[row] : 0.f;
#pragma unroll
                for (int j = 0; j < FN; ++j) {
                    const int col = cbase + j * 16 + (lane & 15);
                    C[(size_t)row * N + col] = acc[i][j][rr] + bias;
                }
            }
    } else if constexpr (EPI == 0) {
        u16* C = (u16*)Cbase + (size_t)b * sC;
#pragma unroll
        for (int i = 0; i < FM; ++i)
#pragma unroll
            for (int rr = 0; rr < 4; ++rr) {
                const int row = rbase + i * 16 + ((lane >> 4) << 2) + rr;
                const float bias = aux1[row];
#pragma unroll
                for (int j = 0; j < FN; ++j) {
                    const int col = cbase + j * 16 + (lane & 15);
                    C[(size_t)row * N + col] = f2bf(acc[i][j][rr] + bias);
                }
            }
    } else {  // EPI == 2
        u16* C = (u16*)Cbase + (size_t)b * sC;
        const float* a1 = aux1 + ((size_t)t * BB + b) * N;
        const float* a2 = aux2 + (size_t)t * N;
        float bet[FN];
#pragma unroll
        for (int j = 0; j < FN; ++j) {
            const int col = cbase + j * 16 + (lane & 15);
            bet[j] = (a1[col] + a2[col]) * (1.f / 3.f);
        }
#pragma unroll
        for (int i = 0; i < FM; ++i)
#pragma unroll
            for (int rr = 0; rr < 4; ++rr) {
                const int row = rbase + i * 16 + ((lane >> 4) << 2) + rr;
#pragma unroll
                for (int j = 0; j < FN; ++j) {
                    const int col = cbase + j * 16 + (lane & 15);
                    float v = acc[i][j][rr] + bet[j];
                    C[(size_t)row * N + col] = f2bf(fmaxf(v, 0.f));
                }
            }
    }
}

// ---------------------------------------------------------------------------
extern "C" void kernel_launch(void* const* d_in, const int* in_sizes, int n_in,
                              void* d_out, int out_size, void* d_ws, size_t ws_size,
                              hipStream_t stream) {
    const float* x  = (const float*)d_in[0];
    const float* W1 = (const float*)d_in[1];
    const float* b1 = (const float*)d_in[2];
    const float* Wl = (const float*)d_in[3];
    const float* bl = (const float*)d_in[4];
    const float* Wr = (const float*)d_in[5];
    const float* Wf = (const float*)d_in[6];
    const float* bf = (const float*)d_in[7];
    const float* W2 = (const float*)d_in[8];
    const float* b2 = (const float*)d_in[9];
    float* y = (float*)d_out;

    // workspace layout (u16 elements)
    u16* wsS   = (u16*)d_ws;
    u16* xT    = wsS;                       // [64][1024][256] = 16,777,216
    u16* h     = wsS + 16777216;            // [64][256][1024] = 16,777,216
    u16* r     = wsS + 33554432;            // [64][256][512]  =  8,388,608
    u16* W1T   = wsS + 41943040;            // [256][256]
    u16* W2T   = wsS + 42008576;            // [256][256]
    u16* WfT   = wsS + 42074112;            // [1024][512]
    u16* WsumT = wsS + 42598400;            // [3][512][1024]
    u16* WlTc  = wsS + 44171264;            // [3][512][3072]
    u16* muCat = wsS + 48889856;            // [3][64][3072]
    float* tmp   = (float*)(wsS + 49479680);  // [3][64][512] f32
    float* blsum = tmp + 98304;               // [3][512] f32
    u16* outT = xT;                           // alias: xT dead after G1

    // weight prep + x transpose
    transpose_bf16<<<dim3(8, 8, 1),   256, 0, stream>>>(W1, W1T, 256, 256);
    transpose_bf16<<<dim3(8, 8, 1),   256, 0, stream>>>(W2, W2T, 256, 256);
    transpose_bf16<<<dim3(32, 16, 1), 256, 0, stream>>>(Wf, WfT, 512, 1024);
    transpose_bf16<<<dim3(32, 8, 64), 256, 0, stream>>>(x, xT, 256, 1024);
    wlt_kernel<<<dim3(16, 32, 9), 256, 0, stream>>>(Wl, WlTc);
    wrsumT_kernel<<<dim3(16, 32, 3), 256, 0, stream>>>(Wr, WsumT);
    blsum_kernel<<<dim3(3), dim3(512), 0, stream>>>(bl, blsum);

    // G1: h[b][n][s] = W1T[n][d] . xT[b][s][d] + b1[n]
    gemm_mfma<128, 128, 0, false><<<dim3(8, 2, 64), 256, 0, stream>>>(
        W1T, xT, h, b1, nullptr, 256, 1024, 0, 262144, 262144);
    // mu (reads h)
    mu_kernel<<<dim3(4, 192), 256, 0, stream>>>(h, muCat);
    // Gbeta: tmp[t][b][h] = muCat[t][b][:] . WlTc[t][h][:]
    gemm_mfma<64, 128, 1, false><<<dim3(4, 1, 3), 256, 0, stream>>>(
        muCat, WlTc, tmp, nullptr, nullptr, 3072, 512, 196608, 1572864, 32768);
    // G5: r[b][n][h] = relu( h[b][n][:] . WsumT[t][h][:] + (tmp+blsum)/3 )
    gemm_mfma<64, 128, 2, true><<<dim3(4, 4, 64), 256, 0, stream>>>(
        h, WsumT, r, tmp, blsum, 1024, 512, 262144, 0, 131072);
    // G6: outT[b][f][n] = WfT[f][h] . r[b][n][h] + bf[f]
    gemm_mfma<128, 128, 0, false><<<dim3(2, 8, 64), 256, 0, stream>>>(
        WfT, r, outT, bf, nullptr, 512, 256, 0, 131072, 262144);
    // G7: y[b][d][s] = W2T[d][n] . outT[b][s][n] + b2[d]
    gemm_mfma<128, 128, 3, false><<<dim3(8, 2, 64), 256, 0, stream>>>(
        W2T, outT, y, b2, nullptr, 256, 1024, 0, 262144, 262144);
}

// Round 3
// 191.394 us; speedup vs baseline: 5.0161x; 1.8881x over previous
//
#include <hip/hip_runtime.h>

typedef unsigned short u16;
typedef __attribute__((ext_vector_type(8))) short bf16x8;
typedef __attribute__((ext_vector_type(4))) float f32x4;

// Problem constants
constexpr int BB = 64;     // batch
constexpr int NN = 256;    // nodes (= linear1 out)
constexpr int SS = 1024;   // LP*P spatial (= F)
constexpr int FF = 1024;   // node feature dim
constexpr int HH = 512;    // hidden

// edge bookkeeping: EDGE_TYPES = [AB,BA,AC,CA,BC,CB,AA,BB,CC]
// dst A edges {1,3,6} (src B,C,A); dst B {0,5,7} (src A,C,B); dst C {2,4,8} (src A,B,C)
__device__ const int d_eArr[3][3] = {{1, 3, 6}, {0, 5, 7}, {2, 4, 8}};
// muCat slot: for src type tp, (dst t) -> e' slot with src(eArr[t][e'])==tp
__device__ const int d_slotE[3][3] = {{2, 0, 0}, {0, 2, 1}, {1, 1, 2}};

__device__ __forceinline__ u16 f2bf(float f) {
    union { float f; unsigned u; } v; v.f = f;
    unsigned r = v.u + 0x7FFFu + ((v.u >> 16) & 1u);
    return (u16)(r >> 16);
}
__device__ __forceinline__ float bf2f(u16 h) {
    union { unsigned u; float f; } v; v.u = ((unsigned)h) << 16;
    return v.f;
}

// async global->LDS, 16 bytes per lane
typedef const __attribute__((address_space(1))) void gv_t;
typedef __attribute__((address_space(3))) void lv_t;
__device__ __forceinline__ void gl16(const void* g, void* l) {
    __builtin_amdgcn_global_load_lds((gv_t*)g, (lv_t*)l, 16, 0, 0);
}
// 16B-slot swizzle value per LDS row (keeps ds_read_b128 <=2-way per 8-lane phase)
__device__ __forceinline__ int swzv(int r) { return (r ^ (r >> 2)) & 3; }

// G5 grouped-row decode: m-tile g -> global (b*256+n) for local row r (0..127)
__device__ __forceinline__ int g5row(int t, int g, int r) {
    if (t == 0) return (g << 8) + r;
    const int bp = (t == 1) ? (g - 64) : (g - 96);
    const int b  = (bp << 1) + (r >> 6);
    const int n  = ((t == 1) ? 128 : 192) + (r & 63);
    return (b << 8) + n;
}

// ---------------------------------------------------------------------------
// Batched transpose fp32 -> bf16: out[b][c][r] = in[b][r][c]
// ---------------------------------------------------------------------------
__global__ __launch_bounds__(256)
void transpose_bf16(const float* __restrict__ in, u16* __restrict__ out, int R, int C) {
    __shared__ float tile[32][33];
    const int b = blockIdx.z;
    in  += (size_t)b * R * C;
    out += (size_t)b * R * C;
    const int c0 = blockIdx.x * 32, r0 = blockIdx.y * 32;
    const int x = threadIdx.x & 31, y = threadIdx.x >> 5;
#pragma unroll
    for (int k = 0; k < 4; ++k)
        tile[y + 8 * k][x] = in[(size_t)(r0 + y + 8 * k) * C + c0 + x];
    __syncthreads();
#pragma unroll
    for (int k = 0; k < 4; ++k)
        out[(size_t)(c0 + y + 8 * k) * R + r0 + x] = f2bf(tile[x][y + 8 * k]);
}

// ---------------------------------------------------------------------------
// WlTcat[t][h][e'*1024+f] = Wl[eArr[t][e']][f][h]  (bf16)
// ---------------------------------------------------------------------------
__global__ __launch_bounds__(256)
void wlt_kernel(const float* __restrict__ Wl, u16* __restrict__ WlTcat) {
    __shared__ float tile[32][33];
    const int p = blockIdx.z, t = p / 3, ep = p % 3;
    const int e = d_eArr[t][ep];
    const int h0 = blockIdx.x * 32, f0 = blockIdx.y * 32;
    const int x = threadIdx.x & 31, y = threadIdx.x >> 5;
    const float* src = Wl + (size_t)e * FF * HH;
#pragma unroll
    for (int k = 0; k < 4; ++k)
        tile[y + 8 * k][x] = src[(size_t)(f0 + y + 8 * k) * HH + h0 + x];
    __syncthreads();
    u16* dst = WlTcat + (size_t)t * HH * 3072 + (size_t)ep * 1024;
#pragma unroll
    for (int k = 0; k < 4; ++k)
        dst[(size_t)(h0 + y + 8 * k) * 3072 + f0 + x] = f2bf(tile[x][y + 8 * k]);
}

// ---------------------------------------------------------------------------
// WsumT[t][h][f] = (1/3) * sum_{e in dst t} Wr[e][f][h]  (bf16)
// ---------------------------------------------------------------------------
__global__ __launch_bounds__(256)
void wrsumT_kernel(const float* __restrict__ Wr, u16* __restrict__ WsumT) {
    __shared__ float tile[32][33];
    const int t = blockIdx.z;
    const int h0 = blockIdx.x * 32, f0 = blockIdx.y * 32;
    const int x = threadIdx.x & 31, y = threadIdx.x >> 5;
    const int e0 = d_eArr[t][0], e1 = d_eArr[t][1], e2 = d_eArr[t][2];
#pragma unroll
    for (int k = 0; k < 4; ++k) {
        const size_t off = (size_t)(f0 + y + 8 * k) * HH + h0 + x;
        float s = Wr[(size_t)e0 * FF * HH + off] + Wr[(size_t)e1 * FF * HH + off] +
                  Wr[(size_t)e2 * FF * HH + off];
        tile[y + 8 * k][x] = s * (1.f / 3.f);
    }
    __syncthreads();
    u16* dst = WsumT + (size_t)t * HH * FF;
#pragma unroll
    for (int k = 0; k < 4; ++k)
        dst[(size_t)(h0 + y + 8 * k) * FF + f0 + x] = f2bf(tile[x][y + 8 * k]);
}

// ---------------------------------------------------------------------------
// mu over node slices, ushort4-vectorized, replicated into muCat[3][64][3072]
// grid (192) block 256: block = (tp, b); thread covers 4 f's
// ---------------------------------------------------------------------------
__global__ __launch_bounds__(256)
void mu_kernel(const u16* __restrict__ h, u16* __restrict__ muCat) {
    const int bid = blockIdx.x;
    const int tp  = bid >> 6;
    const int b   = bid & 63;
    const int lo  = (tp == 0) ? 0 : (tp == 1 ? 128 : 192);
    const int cnt = (tp == 0) ? 128 : 64;
    const int f4  = threadIdx.x << 2;
    const u16* hb = h + ((size_t)b * NN + lo) * SS + f4;
    float s0 = 0.f, s1 = 0.f, s2 = 0.f, s3 = 0.f;
    for (int n = 0; n < cnt; ++n) {
        const ushort4 v = *(const ushort4*)(hb + (size_t)n * SS);
        s0 += bf2f(v.x); s1 += bf2f(v.y); s2 += bf2f(v.z); s3 += bf2f(v.w);
    }
    const float sc = 1.0f / cnt;
    ushort4 o;
    o.x = f2bf(s0 * sc); o.y = f2bf(s1 * sc); o.z = f2bf(s2 * sc); o.w = f2bf(s3 * sc);
#pragma unroll
    for (int t = 0; t < 3; ++t) {
        const int ep = d_slotE[tp][t];
        *(ushort4*)(muCat + ((size_t)t * BB + b) * 3072 + (size_t)ep * 1024 + f4) = o;
    }
}

// ---------------------------------------------------------------------------
// blsum[t][h] = sum_{e in dst t} bl[e][h]   (fp32)
// ---------------------------------------------------------------------------
__global__ void blsum_kernel(const float* __restrict__ bl, float* __restrict__ blsum) {
    const int t = blockIdx.x, hh = threadIdx.x;
    blsum[t * HH + hh] = bl[d_eArr[t][0] * HH + hh] + bl[d_eArr[t][1] * HH + hh] +
                         bl[d_eArr[t][2] * HH + hh];
}

// ---------------------------------------------------------------------------
// beta partial reduce: tmp[i] = sum_ks tmp8[ks][i]
// ---------------------------------------------------------------------------
__global__ __launch_bounds__(256)
void beta_reduce(const float* __restrict__ tmp8, float* __restrict__ tmp) {
    const int i = blockIdx.x * 256 + threadIdx.x;   // 98304 total
    float s = 0.f;
#pragma unroll
    for (int k = 0; k < 8; ++k) s += tmp8[(size_t)k * 98304 + i];
    tmp[i] = s;
}

// ---------------------------------------------------------------------------
// MFMA GEMM, m97-structure: global_load_lds(16B) staging, double-buffered LDS,
// one barrier per K-step. C[M][N] = A[M][K] * (Bt[N][K])^T (+ epilogue).
// 256 threads = 4 waves (2x2), wave tile WMxWN, 16x16x32 bf16 MFMA.
// EPI: 0 bf16 out + aux1[row] | 1 f32 partial (beta, MODE2) |
//      2 G5 (bf16, beta-add + relu) | 3 f32 out + aux1[row]
// MODE: 0 batched (z=b, A shared) | 1 G5 grouped rows (y=g) | 2 beta K-split
// ---------------------------------------------------------------------------
template<int BM, int BN, int KLEN, int EPI, int MODE>
__global__ __launch_bounds__(256)
void gemm2(const u16* __restrict__ Abase, const u16* __restrict__ Bbase,
           void* __restrict__ Cbase, const float* __restrict__ aux1,
           const float* __restrict__ aux2,
           long long sB, long long sC, int ldA, int ldB, int ldC)
{
    constexpr int WM = BM / 2, WN = BN / 2;
    constexpr int FM = WM / 16, FN = WN / 16;
    constexpr int NIA = (BM * 4) / 256, NIB = (BN * 4) / 256;
    constexpr int BUFB = (BM + BN) * 64;     // bytes per buffer (A then B)
    constexpr int NT = KLEN / 32;
    __shared__ __align__(16) unsigned char smem[2 * BUFB];

    const int tid = threadIdx.x, lane = tid & 63, wave = tid >> 6;
    const int wm = wave >> 1, wn = wave & 1;
    const int n0 = blockIdx.x * BN;

    int m0 = 0, b = 0, t = 0, g = 0;
    const u16* Ab; const u16* Bb;
    if constexpr (MODE == 0) {
        b  = blockIdx.z;
        m0 = blockIdx.y * BM;
        Ab = Abase + (size_t)m0 * ldA;
        Bb = Bbase + (size_t)b * sB + (size_t)n0 * ldB;
    } else if constexpr (MODE == 1) {
        g  = blockIdx.y;
        t  = (g < 64) ? 0 : (g < 96 ? 1 : 2);
        Ab = Abase;
        Bb = Bbase + (size_t)t * (HH * FF) + (size_t)n0 * ldB;
    } else {                       // MODE 2: z=t, y=ksplit
        t  = blockIdx.z;
        const int k0 = blockIdx.y * KLEN;
        Ab = Abase + (size_t)t * 64 * ldA + k0;
        Bb = Bbase + (size_t)t * (HH * 3072) + (size_t)n0 * ldB + k0;
    }

    // staging addresses: chunk c -> LDS byte c*16 (linear), global src pre-swizzled
    const u16* gAp[NIA]; const u16* gBp[NIB];
    int lAo[NIA], lBo[NIB];
#pragma unroll
    for (int i = 0; i < NIA; ++i) {
        const int c = i * 256 + tid, r = c >> 2, jl = c & 3;
        const int js = jl ^ swzv(r);
        size_t rowoff;
        if constexpr (MODE == 1) rowoff = (size_t)g5row(t, g, r) * FF;
        else                     rowoff = (size_t)r * ldA;
        gAp[i] = Ab + rowoff + js * 8;
        lAo[i] = c * 16;
    }
#pragma unroll
    for (int i = 0; i < NIB; ++i) {
        const int c = i * 256 + tid, r = c >> 2, jl = c & 3;
        const int js = jl ^ swzv(r);
        gBp[i] = Bb + (size_t)r * ldB + js * 8;
        lBo[i] = BM * 64 + c * 16;
    }
    // fragment read byte offsets (same swizzle on read side)
    const int q = lane >> 4;
    int rAo[FM], rBo[FN];
#pragma unroll
    for (int i = 0; i < FM; ++i) {
        const int r = wm * WM + i * 16 + (lane & 15);
        rAo[i] = (r * 4 + (q ^ swzv(r))) * 16;
    }
#pragma unroll
    for (int j = 0; j < FN; ++j) {
        const int r = wn * WN + j * 16 + (lane & 15);
        rBo[j] = BM * 64 + (r * 4 + (q ^ swzv(r))) * 16;
    }

    char* sm = (char*)smem;
    auto stage = [&](int bufsel, int kofs) {
#pragma unroll
        for (int i = 0; i < NIA; ++i)
            gl16(gAp[i] + kofs, sm + bufsel * BUFB + lAo[i]);
#pragma unroll
        for (int i = 0; i < NIB; ++i)
            gl16(gBp[i] + kofs, sm + bufsel * BUFB + lBo[i]);
    };

    const f32x4 zero4 = {0.f, 0.f, 0.f, 0.f};
    f32x4 acc[FM][FN];
#pragma unroll
    for (int i = 0; i < FM; ++i)
#pragma unroll
        for (int j = 0; j < FN; ++j) acc[i][j] = zero4;

    stage(0, 0);
    __syncthreads();                       // vmcnt drain + barrier: buf0 ready
#pragma unroll 2
    for (int it = 0; it < NT; ++it) {
        const int cur = it & 1;
        if (it + 1 < NT) stage(cur ^ 1, (it + 1) * 32);   // loads fly under MFMA
        bf16x8 af[FM], bq[FN];
#pragma unroll
        for (int i = 0; i < FM; ++i) af[i] = *(const bf16x8*)(sm + cur * BUFB + rAo[i]);
#pragma unroll
        for (int j = 0; j < FN; ++j) bq[j] = *(const bf16x8*)(sm + cur * BUFB + rBo[j]);
#pragma unroll
        for (int i = 0; i < FM; ++i)
#pragma unroll
            for (int j = 0; j < FN; ++j)
                acc[i][j] = __builtin_amdgcn_mfma_f32_16x16x32_bf16(af[i], bq[j], acc[i][j], 0, 0, 0);
        __syncthreads();                   // drains next-tile loads + WAR safety
    }

    // ---------------- epilogue ----------------
    const int q4   = q << 2;
    const int colb = n0 + wn * WN + (lane & 15);
    if constexpr (EPI == 0) {
        u16* C = (u16*)Cbase + (size_t)b * sC;
#pragma unroll
        for (int i = 0; i < FM; ++i)
#pragma unroll
            for (int rr = 0; rr < 4; ++rr) {
                const int row = m0 + wm * WM + i * 16 + q4 + rr;
                const float bias = aux1[row];
#pragma unroll
                for (int j = 0; j < FN; ++j)
                    C[(size_t)row * ldC + colb + j * 16] = f2bf(acc[i][j][rr] + bias);
            }
    } else if constexpr (EPI == 3) {
        float* C = (float*)Cbase + (size_t)b * sC;
#pragma unroll
        for (int i = 0; i < FM; ++i)
#pragma unroll
            for (int rr = 0; rr < 4; ++rr) {
                const int row = m0 + wm * WM + i * 16 + q4 + rr;
                const float bias = aux1[row];
#pragma unroll
                for (int j = 0; j < FN; ++j)
                    C[(size_t)row * ldC + colb + j * 16] = acc[i][j][rr] + bias;
            }
    } else if constexpr (EPI == 1) {       // beta partials: [ks][t][64][512]
        float* C = (float*)Cbase + (size_t)blockIdx.y * 98304 + (size_t)t * (64 * HH);
#pragma unroll
        for (int i = 0; i < FM; ++i)
#pragma unroll
            for (int rr = 0; rr < 4; ++rr) {
                const int row = wm * WM + i * 16 + q4 + rr;
#pragma unroll
                for (int j = 0; j < FN; ++j)
                    C[(size_t)row * HH + colb + j * 16] = acc[i][j][rr];
            }
    } else {                               // EPI == 2 (G5)
        u16* C = (u16*)Cbase;
        const int bb = (t == 0) ? g : ((((t == 1) ? (g - 64) : (g - 96)) << 1) + wm);
        float bet[FN];
#pragma unroll
        for (int j = 0; j < FN; ++j) {
            const int col = colb + j * 16;
            bet[j] = (aux1[((t << 6) + bb) * HH + col] + aux2[t * HH + col]) * (1.f / 3.f);
        }
#pragma unroll
        for (int i = 0; i < FM; ++i)
#pragma unroll
            for (int rr = 0; rr < 4; ++rr) {
                const int rl = wm * WM + i * 16 + q4 + rr;
                const int glob = g5row(t, g, rl);          // b*256+n
#pragma unroll
                for (int j = 0; j < FN; ++j) {
                    const float v = acc[i][j][rr] + bet[j];
                    C[(size_t)glob * ldC + colb + j * 16] = f2bf(fmaxf(v, 0.f));
                }
            }
    }
}

// ---------------------------------------------------------------------------
extern "C" void kernel_launch(void* const* d_in, const int* in_sizes, int n_in,
                              void* d_out, int out_size, void* d_ws, size_t ws_size,
                              hipStream_t stream) {
    const float* x  = (const float*)d_in[0];
    const float* W1 = (const float*)d_in[1];
    const float* b1 = (const float*)d_in[2];
    const float* Wl = (const float*)d_in[3];
    const float* bl = (const float*)d_in[4];
    const float* Wr = (const float*)d_in[5];
    const float* Wf = (const float*)d_in[6];
    const float* bf = (const float*)d_in[7];
    const float* W2 = (const float*)d_in[8];
    const float* b2 = (const float*)d_in[9];
    float* y = (float*)d_out;

    // workspace layout (u16 elements)
    u16* wsS   = (u16*)d_ws;
    u16* xT    = wsS;                       // [64][1024][256] = 16,777,216
    u16* h     = wsS + 16777216;            // [64][256][1024] = 16,777,216
    u16* r     = wsS + 33554432;            // [64][256][512]  =  8,388,608
    u16* W1T   = wsS + 41943040;            // [256][256]
    u16* W2T   = wsS + 42008576;            // [256][256]
    u16* WfT   = wsS + 42074112;            // [1024][512]
    u16* WsumT = wsS + 42598400;            // [3][512][1024]
    u16* WlTc  = wsS + 44171264;            // [3][512][3072]
    u16* muCat = wsS + 48889856;            // [3][64][3072]
    float* tmp   = (float*)(wsS + 49479680);  // [3][64][512] f32
    float* blsum = tmp + 98304;               // [3][512] f32
    float* tmp8  = (float*)r;                 // [8][3][64][512] f32 (dead before G5)
    u16* outT = xT;                           // alias: xT dead after G1

    // weight prep + x transpose
    transpose_bf16<<<dim3(8, 8, 1),   256, 0, stream>>>(W1, W1T, 256, 256);
    transpose_bf16<<<dim3(8, 8, 1),   256, 0, stream>>>(W2, W2T, 256, 256);
    transpose_bf16<<<dim3(32, 16, 1), 256, 0, stream>>>(Wf, WfT, 512, 1024);
    transpose_bf16<<<dim3(32, 8, 64), 256, 0, stream>>>(x, xT, 256, 1024);
    wlt_kernel<<<dim3(16, 32, 9), 256, 0, stream>>>(Wl, WlTc);
    wrsumT_kernel<<<dim3(16, 32, 3), 256, 0, stream>>>(Wr, WsumT);
    blsum_kernel<<<dim3(3), dim3(512), 0, stream>>>(bl, blsum);

    // G1: h[b][n][s] = W1T[n][d] . xT[b][s][d] + b1[n]
    gemm2<128, 128, 256, 0, 0><<<dim3(8, 2, 64), 256, 0, stream>>>(
        W1T, xT, h, b1, nullptr, 262144, 262144, 256, 256, 1024);
    // mu (reads h)
    mu_kernel<<<dim3(192), 256, 0, stream>>>(h, muCat);
    // beta partials: tmp8[ks][t][b][h] += muCat[t][b][kslice] . WlTc[t][h][kslice]
    gemm2<64, 64, 384, 1, 2><<<dim3(8, 8, 3), 256, 0, stream>>>(
        muCat, WlTc, tmp8, nullptr, nullptr, 0, 0, 3072, 3072, 512);
    beta_reduce<<<dim3(384), 256, 0, stream>>>(tmp8, tmp);
    // G5: r[b][n][h] = relu( h[b][n][:] . WsumT[t][h][:] + (tmp+blsum)/3 )
    gemm2<128, 128, 1024, 2, 1><<<dim3(4, 128, 1), 256, 0, stream>>>(
        h, WsumT, r, tmp, blsum, 0, 0, 1024, 1024, 512);
    // G6: outT[b][f][n] = WfT[f][h] . r[b][n][h] + bf[f]
    gemm2<128, 128, 512, 0, 0><<<dim3(2, 8, 64), 256, 0, stream>>>(
        WfT, r, outT, bf, nullptr, 131072, 262144, 512, 512, 256);
    // G7: y[b][d][s] = W2T[d][n] . outT[b][s][n] + b2[d]
    gemm2<128, 128, 256, 3, 0><<<dim3(8, 2, 64), 256, 0, stream>>>(
        W2T, outT, y, b2, nullptr, 262144, 262144, 256, 256, 1024);
}

// Round 4
// 165.049 us; speedup vs baseline: 5.8168x; 1.1596x over previous
//
#include <hip/hip_runtime.h>

typedef unsigned short u16;
typedef __attribute__((ext_vector_type(8))) short bf16x8;
typedef __attribute__((ext_vector_type(4))) float f32x4;

// Problem constants
constexpr int BB = 64;     // batch
constexpr int NN = 256;    // nodes (= linear1 out)
constexpr int SS = 1024;   // LP*P spatial (= F)
constexpr int FF = 1024;   // node feature dim
constexpr int HH = 512;    // hidden

// edge bookkeeping: EDGE_TYPES = [AB,BA,AC,CA,BC,CB,AA,BB,CC]
// dst A edges {1,3,6} (src B,C,A); dst B {0,5,7} (src A,C,B); dst C {2,4,8} (src A,B,C)
__device__ const int d_eArr[3][3] = {{1, 3, 6}, {0, 5, 7}, {2, 4, 8}};
// muCat slot: for src type tp, (dst t) -> e' slot with src(eArr[t][e'])==tp
__device__ const int d_slotE[3][3] = {{2, 0, 0}, {0, 2, 1}, {1, 1, 2}};

__device__ __forceinline__ u16 f2bf(float f) {
    union { float f; unsigned u; } v; v.f = f;
    unsigned r = v.u + 0x7FFFu + ((v.u >> 16) & 1u);
    return (u16)(r >> 16);
}
__device__ __forceinline__ float bf2f(u16 h) {
    union { unsigned u; float f; } v; v.u = ((unsigned)h) << 16;
    return v.f;
}

// async global->LDS, 16 bytes per lane
typedef const __attribute__((address_space(1))) void gv_t;
typedef __attribute__((address_space(3))) void lv_t;
__device__ __forceinline__ void gl16(const void* g, void* l) {
    __builtin_amdgcn_global_load_lds((gv_t*)g, (lv_t*)l, 16, 0, 0);
}
// 16B-slot swizzle value per LDS row (keeps ds_read_b128 conflict-free per 8-lane phase)
__device__ __forceinline__ int swzv(int r) { return (r ^ (r >> 2)) & 3; }

// counted vmcnt waits (immediate must be literal -> template specializations)
template<int N> __device__ __forceinline__ void waitvm();
template<> __device__ __forceinline__ void waitvm<0>() { asm volatile("s_waitcnt vmcnt(0)" ::: "memory"); }
template<> __device__ __forceinline__ void waitvm<2>() { asm volatile("s_waitcnt vmcnt(2)" ::: "memory"); }
template<> __device__ __forceinline__ void waitvm<4>() { asm volatile("s_waitcnt vmcnt(4)" ::: "memory"); }
template<> __device__ __forceinline__ void waitvm<8>() { asm volatile("s_waitcnt vmcnt(8)" ::: "memory"); }

// G5 grouped-row decode: m-tile g -> global (b*256+n) for local row r (0..127)
__device__ __forceinline__ int g5row(int t, int g, int r) {
    if (t == 0) return (g << 8) + r;
    const int bp = (t == 1) ? (g - 64) : (g - 96);
    const int b  = (bp << 1) + (r >> 6);
    const int n  = ((t == 1) ? 128 : 192) + (r & 63);
    return (b << 8) + n;
}

// ---------------------------------------------------------------------------
// Batched transpose fp32 -> bf16: out[b][c][r] = in[b][r][c]  (x only)
// ---------------------------------------------------------------------------
__global__ __launch_bounds__(256)
void transpose_bf16(const float* __restrict__ in, u16* __restrict__ out, int R, int C) {
    __shared__ float tile[32][33];
    const int b = blockIdx.z;
    in  += (size_t)b * R * C;
    out += (size_t)b * R * C;
    const int c0 = blockIdx.x * 32, r0 = blockIdx.y * 32;
    const int x = threadIdx.x & 31, y = threadIdx.x >> 5;
#pragma unroll
    for (int k = 0; k < 4; ++k)
        tile[y + 8 * k][x] = in[(size_t)(r0 + y + 8 * k) * C + c0 + x];
    __syncthreads();
#pragma unroll
    for (int k = 0; k < 4; ++k)
        out[(size_t)(c0 + y + 8 * k) * R + r0 + x] = f2bf(tile[x][y + 8 * k]);
}

// ---------------------------------------------------------------------------
// Combined weight prep: W1T, W2T, WfT transposes + WlTcat + WsumT + blsum
// one launch, block-range dispatch. 256 threads/block.
// ---------------------------------------------------------------------------
__device__ __forceinline__ void tr32(const float* __restrict__ in, u16* __restrict__ out,
                                     int R, int C, int bx, int by, float (*tile)[33]) {
    const int c0 = bx * 32, r0 = by * 32;
    const int x = threadIdx.x & 31, y = threadIdx.x >> 5;
#pragma unroll
    for (int k = 0; k < 4; ++k)
        tile[y + 8 * k][x] = in[(size_t)(r0 + y + 8 * k) * C + c0 + x];
    __syncthreads();
#pragma unroll
    for (int k = 0; k < 4; ++k)
        out[(size_t)(c0 + y + 8 * k) * R + r0 + x] = f2bf(tile[x][y + 8 * k]);
}

__global__ __launch_bounds__(256)
void prep_weights(const float* __restrict__ W1, const float* __restrict__ W2,
                  const float* __restrict__ Wf, const float* __restrict__ Wl,
                  const float* __restrict__ Wr, const float* __restrict__ bl,
                  u16* __restrict__ W1T, u16* __restrict__ W2T, u16* __restrict__ WfT,
                  u16* __restrict__ WlTc, u16* __restrict__ WsumT, float* __restrict__ blsum)
{
    __shared__ float tile[32][33];
    int id = blockIdx.x;
    if (id < 64) { tr32(W1, W1T, 256, 256, id & 7, id >> 3, tile); return; }
    id -= 64;
    if (id < 64) { tr32(W2, W2T, 256, 256, id & 7, id >> 3, tile); return; }
    id -= 64;
    if (id < 512) { tr32(Wf, WfT, 512, 1024, id & 31, id >> 5, tile); return; }
    id -= 512;
    if (id < 4608) {                       // WlTcat[t][h][e'*1024+f] = Wl[e][f][h]
        const int p = id >> 9, rem = id & 511;
        const int bx = rem & 15, by = rem >> 4;
        const int t = p / 3, ep = p % 3, e = d_eArr[t][ep];
        const int h0 = bx * 32, f0 = by * 32;
        const int x = threadIdx.x & 31, y = threadIdx.x >> 5;
        const float* src = Wl + (size_t)e * FF * HH;
#pragma unroll
        for (int k = 0; k < 4; ++k)
            tile[y + 8 * k][x] = src[(size_t)(f0 + y + 8 * k) * HH + h0 + x];
        __syncthreads();
        u16* dst = WlTc + (size_t)t * HH * 3072 + (size_t)ep * 1024;
#pragma unroll
        for (int k = 0; k < 4; ++k)
            dst[(size_t)(h0 + y + 8 * k) * 3072 + f0 + x] = f2bf(tile[x][y + 8 * k]);
        return;
    }
    id -= 4608;
    if (id < 1536) {                       // WsumT[t][h][f] = (1/3) sum Wr[e][f][h]
        const int t = id >> 9, rem = id & 511;
        const int bx = rem & 15, by = rem >> 4;
        const int h0 = bx * 32, f0 = by * 32;
        const int x = threadIdx.x & 31, y = threadIdx.x >> 5;
        const int e0 = d_eArr[t][0], e1 = d_eArr[t][1], e2 = d_eArr[t][2];
#pragma unroll
        for (int k = 0; k < 4; ++k) {
            const size_t off = (size_t)(f0 + y + 8 * k) * HH + h0 + x;
            float s = Wr[(size_t)e0 * FF * HH + off] + Wr[(size_t)e1 * FF * HH + off] +
                      Wr[(size_t)e2 * FF * HH + off];
            tile[y + 8 * k][x] = s * (1.f / 3.f);
        }
        __syncthreads();
        u16* dst = WsumT + (size_t)t * HH * FF;
#pragma unroll
        for (int k = 0; k < 4; ++k)
            dst[(size_t)(h0 + y + 8 * k) * FF + f0 + x] = f2bf(tile[x][y + 8 * k]);
        return;
    }
    // blsum: 1536 values, 6 per thread
#pragma unroll
    for (int j = 0; j < 6; ++j) {
        const int idx = j * 256 + threadIdx.x;
        const int t = idx >> 9, hh = idx & 511;
        blsum[t * HH + hh] = bl[d_eArr[t][0] * HH + hh] + bl[d_eArr[t][1] * HH + hh] +
                             bl[d_eArr[t][2] * HH + hh];
    }
}

// ---------------------------------------------------------------------------
// mu over node slices, ushort4-vectorized, replicated into muCat[3][64][3072]
// ---------------------------------------------------------------------------
__global__ __launch_bounds__(256)
void mu_kernel(const u16* __restrict__ h, u16* __restrict__ muCat) {
    const int bid = blockIdx.x;
    const int tp  = bid >> 6;
    const int b   = bid & 63;
    const int lo  = (tp == 0) ? 0 : (tp == 1 ? 128 : 192);
    const int cnt = (tp == 0) ? 128 : 64;
    const int f4  = threadIdx.x << 2;
    const u16* hb = h + ((size_t)b * NN + lo) * SS + f4;
    float s0 = 0.f, s1 = 0.f, s2 = 0.f, s3 = 0.f;
    for (int n = 0; n < cnt; ++n) {
        const ushort4 v = *(const ushort4*)(hb + (size_t)n * SS);
        s0 += bf2f(v.x); s1 += bf2f(v.y); s2 += bf2f(v.z); s3 += bf2f(v.w);
    }
    const float sc = 1.0f / cnt;
    ushort4 o;
    o.x = f2bf(s0 * sc); o.y = f2bf(s1 * sc); o.z = f2bf(s2 * sc); o.w = f2bf(s3 * sc);
#pragma unroll
    for (int t = 0; t < 3; ++t) {
        const int ep = d_slotE[tp][t];
        *(ushort4*)(muCat + ((size_t)t * BB + b) * 3072 + (size_t)ep * 1024 + f4) = o;
    }
}

// ---------------------------------------------------------------------------
// beta partial reduce: tmp[i] = sum_ks tmp8[ks][i]
// ---------------------------------------------------------------------------
__global__ __launch_bounds__(256)
void beta_reduce(const float* __restrict__ tmp8, float* __restrict__ tmp) {
    const int i = blockIdx.x * 256 + threadIdx.x;   // 98304 total
    float s = 0.f;
#pragma unroll
    for (int k = 0; k < 8; ++k) s += tmp8[(size_t)k * 98304 + i];
    tmp[i] = s;
}

// ---------------------------------------------------------------------------
// MFMA GEMM: global_load_lds staging, 3-deep rotating LDS buffers,
// counted vmcnt (never drains pipeline), raw s_barrier. m201-pattern.
// C[M][N] = A[M][K] * (Bt[N][K])^T (+ epilogue).
// 256 threads = 4 waves (2x2), 16x16x32 bf16 MFMA.
// EPI: 0 bf16 out + aux1[row] | 1 f32 partial (beta, MODE2) |
//      2 G5 (bf16, beta-add + relu) | 3 f32 out + aux1[row]
// MODE: 0 batched (z=b, A shared) | 1 G5 grouped rows (y=g) | 2 beta K-split
// ---------------------------------------------------------------------------
template<int BM, int BN, int KLEN, int EPI, int MODE>
__global__ __launch_bounds__(256)
void gemm2(const u16* __restrict__ Abase, const u16* __restrict__ Bbase,
           void* __restrict__ Cbase, const float* __restrict__ aux1,
           const float* __restrict__ aux2,
           long long sB, long long sC, int ldA, int ldB, int ldC)
{
    constexpr int WM = BM / 2, WN = BN / 2;
    constexpr int FM = WM / 16, FN = WN / 16;
    constexpr int NIA = (BM * 4) / 256, NIB = (BN * 4) / 256;
    constexpr int LPS = NIA + NIB;           // loads per stage per thread
    constexpr int BUFB = (BM + BN) * 64;     // bytes per buffer (A then B)
    constexpr int NT = KLEN / 32;
    static_assert(NT >= 3, "need >=3 K-steps");
    __shared__ __align__(16) unsigned char smem[3 * BUFB];

    const int tid = threadIdx.x, lane = tid & 63, wave = tid >> 6;
    const int wm = wave >> 1, wn = wave & 1;
    const int n0 = blockIdx.x * BN;

    int m0 = 0, b = 0, t = 0, g = 0;
    const u16* Ab; const u16* Bb;
    if constexpr (MODE == 0) {
        b  = blockIdx.z;
        m0 = blockIdx.y * BM;
        Ab = Abase + (size_t)m0 * ldA;
        Bb = Bbase + (size_t)b * sB + (size_t)n0 * ldB;
    } else if constexpr (MODE == 1) {
        g  = blockIdx.y;
        t  = (g < 64) ? 0 : (g < 96 ? 1 : 2);
        Ab = Abase;
        Bb = Bbase + (size_t)t * (HH * FF) + (size_t)n0 * ldB;
    } else {                       // MODE 2: z=t, y=ksplit
        t  = blockIdx.z;
        const int k0 = blockIdx.y * KLEN;
        Ab = Abase + (size_t)t * 64 * ldA + k0;
        Bb = Bbase + (size_t)t * (HH * 3072) + (size_t)n0 * ldB + k0;
    }

    // staging addresses: chunk c -> LDS byte c*16 (linear), global src pre-swizzled
    const u16* gAp[NIA]; const u16* gBp[NIB];
    int lAo[NIA], lBo[NIB];
#pragma unroll
    for (int i = 0; i < NIA; ++i) {
        const int c = i * 256 + tid, r = c >> 2, jl = c & 3;
        const int js = jl ^ swzv(r);
        size_t rowoff;
        if constexpr (MODE == 1) rowoff = (size_t)g5row(t, g, r) * FF;
        else                     rowoff = (size_t)r * ldA;
        gAp[i] = Ab + rowoff + js * 8;
        lAo[i] = c * 16;
    }
#pragma unroll
    for (int i = 0; i < NIB; ++i) {
        const int c = i * 256 + tid, r = c >> 2, jl = c & 3;
        const int js = jl ^ swzv(r);
        gBp[i] = Bb + (size_t)r * ldB + js * 8;
        lBo[i] = BM * 64 + c * 16;
    }
    // fragment read byte offsets (same swizzle on read side)
    const int q = lane >> 4;
    int rAo[FM], rBo[FN];
#pragma unroll
    for (int i = 0; i < FM; ++i) {
        const int r = wm * WM + i * 16 + (lane & 15);
        rAo[i] = (r * 4 + (q ^ swzv(r))) * 16;
    }
#pragma unroll
    for (int j = 0; j < FN; ++j) {
        const int r = wn * WN + j * 16 + (lane & 15);
        rBo[j] = BM * 64 + (r * 4 + (q ^ swzv(r))) * 16;
    }

    char* sm = (char*)smem;
    auto stage = [&](int bufo, int it) {
        const int kofs = it * 32;
#pragma unroll
        for (int i = 0; i < NIA; ++i)
            gl16(gAp[i] + kofs, sm + bufo + lAo[i]);
#pragma unroll
        for (int i = 0; i < NIB; ++i)
            gl16(gBp[i] + kofs, sm + bufo + lBo[i]);
    };

    const f32x4 zero4 = {0.f, 0.f, 0.f, 0.f};
    f32x4 acc[FM][FN];
#pragma unroll
    for (int i = 0; i < FM; ++i)
#pragma unroll
        for (int j = 0; j < FN; ++j) acc[i][j] = zero4;

    // prologue: 3 tiles in flight
    stage(0, 0);
    stage(BUFB, 1);
    stage(2 * BUFB, 2);

    int bufo = 0;
    for (int it = 0; it < NT; ++it) {
        // wait for tile `it` only (loads for it+1, it+2 stay in flight)
        if (it < NT - 2)       waitvm<2 * LPS>();
        else if (it == NT - 2) waitvm<LPS>();
        else                   waitvm<0>();
        __builtin_amdgcn_s_barrier();          // all waves' tile-it loads done

        bf16x8 af[FM], bq[FN];
#pragma unroll
        for (int i = 0; i < FM; ++i) af[i] = *(const bf16x8*)(sm + bufo + rAo[i]);
#pragma unroll
        for (int j = 0; j < FN; ++j) bq[j] = *(const bf16x8*)(sm + bufo + rBo[j]);
        asm volatile("s_waitcnt lgkmcnt(0)" ::: "memory");
        __builtin_amdgcn_sched_barrier(0);

        __builtin_amdgcn_s_setprio(1);
#pragma unroll
        for (int i = 0; i < FM; ++i)
#pragma unroll
            for (int j = 0; j < FN; ++j)
                acc[i][j] = __builtin_amdgcn_mfma_f32_16x16x32_bf16(af[i], bq[j], acc[i][j], 0, 0, 0);
        __builtin_amdgcn_s_setprio(0);

        __builtin_amdgcn_s_barrier();          // all waves done reading buf `bufo`
        if (it + 3 < NT) stage(bufo, it + 3);  // restage freed buffer
        bufo = (bufo == 2 * BUFB) ? 0 : bufo + BUFB;
    }

    // ---------------- epilogue ----------------
    const int q4   = q << 2;
    const int colb = n0 + wn * WN + (lane & 15);
    if constexpr (EPI == 0) {
        u16* C = (u16*)Cbase + (size_t)b * sC;
#pragma unroll
        for (int i = 0; i < FM; ++i)
#pragma unroll
            for (int rr = 0; rr < 4; ++rr) {
                const int row = m0 + wm * WM + i * 16 + q4 + rr;
                const float bias = aux1[row];
#pragma unroll
                for (int j = 0; j < FN; ++j)
                    C[(size_t)row * ldC + colb + j * 16] = f2bf(acc[i][j][rr] + bias);
            }
    } else if constexpr (EPI == 3) {
        float* C = (float*)Cbase + (size_t)b * sC;
#pragma unroll
        for (int i = 0; i < FM; ++i)
#pragma unroll
            for (int rr = 0; rr < 4; ++rr) {
                const int row = m0 + wm * WM + i * 16 + q4 + rr;
                const float bias = aux1[row];
#pragma unroll
                for (int j = 0; j < FN; ++j)
                    C[(size_t)row * ldC + colb + j * 16] = acc[i][j][rr] + bias;
            }
    } else if constexpr (EPI == 1) {       // beta partials: [ks][t][64][512]
        float* C = (float*)Cbase + (size_t)blockIdx.y * 98304 + (size_t)t * (64 * HH);
#pragma unroll
        for (int i = 0; i < FM; ++i)
#pragma unroll
            for (int rr = 0; rr < 4; ++rr) {
                const int row = wm * WM + i * 16 + q4 + rr;
#pragma unroll
                for (int j = 0; j < FN; ++j)
                    C[(size_t)row * HH + colb + j * 16] = acc[i][j][rr];
            }
    } else {                               // EPI == 2 (G5)
        u16* C = (u16*)Cbase;
        const int bb = (t == 0) ? g : ((((t == 1) ? (g - 64) : (g - 96)) << 1) + wm);
        float bet[FN];
#pragma unroll
        for (int j = 0; j < FN; ++j) {
            const int col = colb + j * 16;
            bet[j] = (aux1[((t << 6) + bb) * HH + col] + aux2[t * HH + col]) * (1.f / 3.f);
        }
#pragma unroll
        for (int i = 0; i < FM; ++i)
#pragma unroll
            for (int rr = 0; rr < 4; ++rr) {
                const int rl = wm * WM + i * 16 + q4 + rr;
                const int glob = g5row(t, g, rl);          // b*256+n
#pragma unroll
                for (int j = 0; j < FN; ++j) {
                    const float v = acc[i][j][rr] + bet[j];
                    C[(size_t)glob * ldC + colb + j * 16] = f2bf(fmaxf(v, 0.f));
                }
            }
    }
}

// ---------------------------------------------------------------------------
extern "C" void kernel_launch(void* const* d_in, const int* in_sizes, int n_in,
                              void* d_out, int out_size, void* d_ws, size_t ws_size,
                              hipStream_t stream) {
    const float* x  = (const float*)d_in[0];
    const float* W1 = (const float*)d_in[1];
    const float* b1 = (const float*)d_in[2];
    const float* Wl = (const float*)d_in[3];
    const float* bl = (const float*)d_in[4];
    const float* Wr = (const float*)d_in[5];
    const float* Wf = (const float*)d_in[6];
    const float* bf = (const float*)d_in[7];
    const float* W2 = (const float*)d_in[8];
    const float* b2 = (const float*)d_in[9];
    float* y = (float*)d_out;

    // workspace layout (u16 elements)
    u16* wsS   = (u16*)d_ws;
    u16* xT    = wsS;                       // [64][1024][256] = 16,777,216
    u16* h     = wsS + 16777216;            // [64][256][1024] = 16,777,216
    u16* r     = wsS + 33554432;            // [64][256][512]  =  8,388,608
    u16* W1T   = wsS + 41943040;            // [256][256]
    u16* W2T   = wsS + 42008576;            // [256][256]
    u16* WfT   = wsS + 42074112;            // [1024][512]
    u16* WsumT = wsS + 42598400;            // [3][512][1024]
    u16* WlTc  = wsS + 44171264;            // [3][512][3072]
    u16* muCat = wsS + 48889856;            // [3][64][3072]
    float* tmp   = (float*)(wsS + 49479680);  // [3][64][512] f32
    float* blsum = tmp + 98304;               // [3][512] f32
    float* tmp8  = (float*)r;                 // [8][3][64][512] f32 (dead before G5)
    u16* outT = xT;                           // alias: xT dead after G1

    // weight prep (one launch) + x transpose
    prep_weights<<<dim3(6785), 256, 0, stream>>>(W1, W2, Wf, Wl, Wr, bl,
                                                 W1T, W2T, WfT, WlTc, WsumT, blsum);
    transpose_bf16<<<dim3(32, 8, 64), 256, 0, stream>>>(x, xT, 256, 1024);

    // G1: h[b][n][s] = W1T[n][d] . xT[b][s][d] + b1[n]
    gemm2<128, 128, 256, 0, 0><<<dim3(8, 2, 64), 256, 0, stream>>>(
        W1T, xT, h, b1, nullptr, 262144, 262144, 256, 256, 1024);
    // mu (reads h)
    mu_kernel<<<dim3(192), 256, 0, stream>>>(h, muCat);
    // beta partials: tmp8[ks][t][b][h] += muCat[t][b][kslice] . WlTc[t][h][kslice]
    gemm2<64, 64, 384, 1, 2><<<dim3(8, 8, 3), 256, 0, stream>>>(
        muCat, WlTc, tmp8, nullptr, nullptr, 0, 0, 3072, 3072, 512);
    beta_reduce<<<dim3(384), 256, 0, stream>>>(tmp8, tmp);
    // G5: r[b][n][h] = relu( h[b][n][:] . WsumT[t][h][:] + (tmp+blsum)/3 )
    gemm2<128, 128, 1024, 2, 1><<<dim3(4, 128, 1), 256, 0, stream>>>(
        h, WsumT, r, tmp, blsum, 0, 0, 1024, 1024, 512);
    // G6: outT[b][f][n] = WfT[f][h] . r[b][n][h] + bf[f]
    gemm2<128, 128, 512, 0, 0><<<dim3(2, 8, 64), 256, 0, stream>>>(
        WfT, r, outT, bf, nullptr, 131072, 262144, 512, 512, 256);
    // G7: y[b][d][s] = W2T[d][n] . outT[b][s][n] + b2[d]
    gemm2<128, 128, 256, 3, 0><<<dim3(8, 2, 64), 256, 0, stream>>>(
        W2T, outT, y, b2, nullptr, 262144, 262144, 256, 256, 1024);
}

// Round 5
// 133.196 us; speedup vs baseline: 7.2078x; 1.2391x over previous
//
#include <hip/hip_runtime.h>

typedef unsigned short u16;
typedef __attribute__((ext_vector_type(8))) short bf16x8;
typedef __attribute__((ext_vector_type(4))) float f32x4;

// Problem constants
constexpr int BB = 64;     // batch
constexpr int NN = 256;    // nodes (= linear1 out)
constexpr int SS = 1024;   // LP*P spatial (= F)
constexpr int FF = 1024;   // node feature dim
constexpr int HH = 512;    // hidden

// edge bookkeeping: EDGE_TYPES = [AB,BA,AC,CA,BC,CB,AA,BB,CC]
// dst A edges {1,3,6} (src B,C,A); dst B {0,5,7} (src A,C,B); dst C {2,4,8} (src A,B,C)
__device__ const int d_eArr[3][3] = {{1, 3, 6}, {0, 5, 7}, {2, 4, 8}};
// muCat slot: for src type tp, (dst t) -> e' slot with src(eArr[t][e'])==tp
__device__ const int d_slotE[3][3] = {{2, 0, 0}, {0, 2, 1}, {1, 1, 2}};

__device__ __forceinline__ u16 f2bf(float f) {
    union { float f; unsigned u; } v; v.f = f;
    unsigned r = v.u + 0x7FFFu + ((v.u >> 16) & 1u);
    return (u16)(r >> 16);
}
__device__ __forceinline__ float bf2f(u16 h) {
    union { unsigned u; float f; } v; v.u = ((unsigned)h) << 16;
    return v.f;
}

// async global->LDS, 16 bytes per lane
typedef const __attribute__((address_space(1))) void gv_t;
typedef __attribute__((address_space(3))) void lv_t;
__device__ __forceinline__ void gl16(const void* g, void* l) {
    __builtin_amdgcn_global_load_lds((gv_t*)g, (lv_t*)l, 16, 0, 0);
}
// 16B-slot swizzle value per LDS row (keeps ds_read_b128 conflict-free per 8-lane phase)
__device__ __forceinline__ int swzv(int r) { return (r ^ (r >> 2)) & 3; }

// counted vmcnt waits (immediate must be literal -> template specializations)
template<int N> __device__ __forceinline__ void waitvm();
template<> __device__ __forceinline__ void waitvm<0>()  { asm volatile("s_waitcnt vmcnt(0)" ::: "memory"); }
template<> __device__ __forceinline__ void waitvm<2>()  { asm volatile("s_waitcnt vmcnt(2)" ::: "memory"); }
template<> __device__ __forceinline__ void waitvm<4>()  { asm volatile("s_waitcnt vmcnt(4)" ::: "memory"); }
template<> __device__ __forceinline__ void waitvm<6>()  { asm volatile("s_waitcnt vmcnt(6)" ::: "memory"); }
template<> __device__ __forceinline__ void waitvm<8>()  { asm volatile("s_waitcnt vmcnt(8)" ::: "memory"); }
template<> __device__ __forceinline__ void waitvm<12>() { asm volatile("s_waitcnt vmcnt(12)" ::: "memory"); }

// G5 grouped-row decode: m-tile g -> global (b*256+n) for local row r (0..127)
__device__ __forceinline__ int g5row(int t, int g, int r) {
    if (t == 0) return (g << 8) + r;
    const int bp = (t == 1) ? (g - 64) : (g - 96);
    const int b  = (bp << 1) + (r >> 6);
    const int n  = ((t == 1) ? 128 : 192) + (r & 63);
    return (b << 8) + n;
}

// ---------------------------------------------------------------------------
// Batched transpose fp32 -> bf16: out[b][c][r] = in[b][r][c]  (x only)
// ---------------------------------------------------------------------------
__global__ __launch_bounds__(256)
void transpose_bf16(const float* __restrict__ in, u16* __restrict__ out, int R, int C) {
    __shared__ float tile[32][33];
    const int b = blockIdx.z;
    in  += (size_t)b * R * C;
    out += (size_t)b * R * C;
    const int c0 = blockIdx.x * 32, r0 = blockIdx.y * 32;
    const int x = threadIdx.x & 31, y = threadIdx.x >> 5;
#pragma unroll
    for (int k = 0; k < 4; ++k)
        tile[y + 8 * k][x] = in[(size_t)(r0 + y + 8 * k) * C + c0 + x];
    __syncthreads();
#pragma unroll
    for (int k = 0; k < 4; ++k)
        out[(size_t)(c0 + y + 8 * k) * R + r0 + x] = f2bf(tile[x][y + 8 * k]);
}

// ---------------------------------------------------------------------------
// Combined weight prep: W1T, W2T, WfT transposes + WlTcat + WsumT + blsum
// ---------------------------------------------------------------------------
__device__ __forceinline__ void tr32(const float* __restrict__ in, u16* __restrict__ out,
                                     int R, int C, int bx, int by, float (*tile)[33]) {
    const int c0 = bx * 32, r0 = by * 32;
    const int x = threadIdx.x & 31, y = threadIdx.x >> 5;
#pragma unroll
    for (int k = 0; k < 4; ++k)
        tile[y + 8 * k][x] = in[(size_t)(r0 + y + 8 * k) * C + c0 + x];
    __syncthreads();
#pragma unroll
    for (int k = 0; k < 4; ++k)
        out[(size_t)(c0 + y + 8 * k) * R + r0 + x] = f2bf(tile[x][y + 8 * k]);
}

__global__ __launch_bounds__(256)
void prep_weights(const float* __restrict__ W1, const float* __restrict__ W2,
                  const float* __restrict__ Wf, const float* __restrict__ Wl,
                  const float* __restrict__ Wr, const float* __restrict__ bl,
                  u16* __restrict__ W1T, u16* __restrict__ W2T, u16* __restrict__ WfT,
                  u16* __restrict__ WlTc, u16* __restrict__ WsumT, float* __restrict__ blsum)
{
    __shared__ float tile[32][33];
    int id = blockIdx.x;
    if (id < 64) { tr32(W1, W1T, 256, 256, id & 7, id >> 3, tile); return; }
    id -= 64;
    if (id < 64) { tr32(W2, W2T, 256, 256, id & 7, id >> 3, tile); return; }
    id -= 64;
    if (id < 512) { tr32(Wf, WfT, 512, 1024, id & 31, id >> 5, tile); return; }
    id -= 512;
    if (id < 4608) {                       // WlTcat[t][h][e'*1024+f] = Wl[e][f][h]
        const int p = id >> 9, rem = id & 511;
        const int bx = rem & 15, by = rem >> 4;
        const int t = p / 3, ep = p % 3, e = d_eArr[t][ep];
        const int h0 = bx * 32, f0 = by * 32;
        const int x = threadIdx.x & 31, y = threadIdx.x >> 5;
        const float* src = Wl + (size_t)e * FF * HH;
#pragma unroll
        for (int k = 0; k < 4; ++k)
            tile[y + 8 * k][x] = src[(size_t)(f0 + y + 8 * k) * HH + h0 + x];
        __syncthreads();
        u16* dst = WlTc + (size_t)t * HH * 3072 + (size_t)ep * 1024;
#pragma unroll
        for (int k = 0; k < 4; ++k)
            dst[(size_t)(h0 + y + 8 * k) * 3072 + f0 + x] = f2bf(tile[x][y + 8 * k]);
        return;
    }
    id -= 4608;
    if (id < 1536) {                       // WsumT[t][h][f] = (1/3) sum Wr[e][f][h]
        const int t = id >> 9, rem = id & 511;
        const int bx = rem & 15, by = rem >> 4;
        const int h0 = bx * 32, f0 = by * 32;
        const int x = threadIdx.x & 31, y = threadIdx.x >> 5;
        const int e0 = d_eArr[t][0], e1 = d_eArr[t][1], e2 = d_eArr[t][2];
#pragma unroll
        for (int k = 0; k < 4; ++k) {
            const size_t off = (size_t)(f0 + y + 8 * k) * HH + h0 + x;
            float s = Wr[(size_t)e0 * FF * HH + off] + Wr[(size_t)e1 * FF * HH + off] +
                      Wr[(size_t)e2 * FF * HH + off];
            tile[y + 8 * k][x] = s * (1.f / 3.f);
        }
        __syncthreads();
        u16* dst = WsumT + (size_t)t * HH * FF;
#pragma unroll
        for (int k = 0; k < 4; ++k)
            dst[(size_t)(h0 + y + 8 * k) * FF + f0 + x] = f2bf(tile[x][y + 8 * k]);
        return;
    }
    // blsum: 1536 values, 6 per thread
#pragma unroll
    for (int j = 0; j < 6; ++j) {
        const int idx = j * 256 + threadIdx.x;
        const int t = idx >> 9, hh = idx & 511;
        blsum[t * HH + hh] = bl[d_eArr[t][0] * HH + hh] + bl[d_eArr[t][1] * HH + hh] +
                             bl[d_eArr[t][2] * HH + hh];
    }
}

// ---------------------------------------------------------------------------
// MFMA GEMM: global_load_lds staging, 3-deep rotating LDS buffers,
// counted vmcnt (never drains pipeline), raw s_barrier.
// C[M][N] = A[M][K] * (Bt[N][K])^T (+ epilogue).
// 256 threads = 4 waves (2x2), 16x16x32 bf16 MFMA.
// EPI: 0 bf16 out + aux1[row] | 1 f32 partial (beta, MODE2) |
//      2 G5 (bf16, 8-partial beta reduce + blsum + relu) | 3 f32 out + aux1[row] |
//      4 bf16 out + aux1[row] + fused mu (requires BM=256 = all n rows)
// MODE: 0 batched (z=b, A shared) | 1 G5 grouped rows (y=g) | 2 beta K-split
// ---------------------------------------------------------------------------
template<int BM, int BN, int KLEN, int EPI, int MODE>
__global__ __launch_bounds__(256, 2)
void gemm2(const u16* __restrict__ Abase, const u16* __restrict__ Bbase,
           void* __restrict__ Cbase, const float* __restrict__ aux1,
           const float* __restrict__ aux2, u16* __restrict__ muOut,
           long long sB, long long sC, int ldA, int ldB, int ldC)
{
    constexpr int WM = BM / 2, WN = BN / 2;
    constexpr int FM = WM / 16, FN = WN / 16;
    constexpr int NIA = (BM * 4) / 256, NIB = (BN * 4) / 256;
    constexpr int LPS = NIA + NIB;           // loads per stage per thread
    constexpr int BUFB = (BM + BN) * 64;     // bytes per buffer (A then B)
    constexpr int NT = KLEN / 32;
    static_assert(NT >= 3, "need >=3 K-steps");
    __shared__ __align__(16) unsigned char smem[3 * BUFB];

    const int tid = threadIdx.x, lane = tid & 63, wave = tid >> 6;
    const int wm = wave >> 1, wn = wave & 1;
    const int n0 = blockIdx.x * BN;

    int m0 = 0, b = 0, t = 0, g = 0;
    const u16* Ab; const u16* Bb;
    if constexpr (MODE == 0) {
        b  = blockIdx.z;
        m0 = blockIdx.y * BM;
        Ab = Abase + (size_t)m0 * ldA;
        Bb = Bbase + (size_t)b * sB + (size_t)n0 * ldB;
    } else if constexpr (MODE == 1) {
        g  = blockIdx.y;
        t  = (g < 64) ? 0 : (g < 96 ? 1 : 2);
        Ab = Abase;
        Bb = Bbase + (size_t)t * (HH * FF) + (size_t)n0 * ldB;
    } else {                       // MODE 2: z=t, y=ksplit
        t  = blockIdx.z;
        const int k0 = blockIdx.y * KLEN;
        Ab = Abase + (size_t)t * 64 * ldA + k0;
        Bb = Bbase + (size_t)t * (HH * 3072) + (size_t)n0 * ldB + k0;
    }

    // staging addresses: chunk c -> LDS byte c*16 (linear), global src pre-swizzled
    const u16* gAp[NIA]; const u16* gBp[NIB];
    int lAo[NIA], lBo[NIB];
#pragma unroll
    for (int i = 0; i < NIA; ++i) {
        const int c = i * 256 + tid, r = c >> 2, jl = c & 3;
        const int js = jl ^ swzv(r);
        size_t rowoff;
        if constexpr (MODE == 1) rowoff = (size_t)g5row(t, g, r) * FF;
        else                     rowoff = (size_t)r * ldA;
        gAp[i] = Ab + rowoff + js * 8;
        lAo[i] = c * 16;
    }
#pragma unroll
    for (int i = 0; i < NIB; ++i) {
        const int c = i * 256 + tid, r = c >> 2, jl = c & 3;
        const int js = jl ^ swzv(r);
        gBp[i] = Bb + (size_t)r * ldB + js * 8;
        lBo[i] = BM * 64 + c * 16;
    }
    // fragment read byte offsets (same swizzle on read side)
    const int q = lane >> 4;
    int rAo[FM], rBo[FN];
#pragma unroll
    for (int i = 0; i < FM; ++i) {
        const int r = wm * WM + i * 16 + (lane & 15);
        rAo[i] = (r * 4 + (q ^ swzv(r))) * 16;
    }
#pragma unroll
    for (int j = 0; j < FN; ++j) {
        const int r = wn * WN + j * 16 + (lane & 15);
        rBo[j] = BM * 64 + (r * 4 + (q ^ swzv(r))) * 16;
    }

    char* sm = (char*)smem;
    auto stage = [&](int bufo, int it) {
        const int kofs = it * 32;
#pragma unroll
        for (int i = 0; i < NIA; ++i)
            gl16(gAp[i] + kofs, sm + bufo + lAo[i]);
#pragma unroll
        for (int i = 0; i < NIB; ++i)
            gl16(gBp[i] + kofs, sm + bufo + lBo[i]);
    };

    const f32x4 zero4 = {0.f, 0.f, 0.f, 0.f};
    f32x4 acc[FM][FN];
#pragma unroll
    for (int i = 0; i < FM; ++i)
#pragma unroll
        for (int j = 0; j < FN; ++j) acc[i][j] = zero4;

    // prologue: 3 tiles in flight
    stage(0, 0);
    stage(BUFB, 1);
    stage(2 * BUFB, 2);

    int bufo = 0;
    for (int it = 0; it < NT; ++it) {
        // wait for tile `it` only (loads for it+1, it+2 stay in flight)
        if (it < NT - 2)       waitvm<2 * LPS>();
        else if (it == NT - 2) waitvm<LPS>();
        else                   waitvm<0>();
        __builtin_amdgcn_s_barrier();          // all waves' tile-it loads done

        bf16x8 af[FM], bq[FN];
#pragma unroll
        for (int i = 0; i < FM; ++i) af[i] = *(const bf16x8*)(sm + bufo + rAo[i]);
#pragma unroll
        for (int j = 0; j < FN; ++j) bq[j] = *(const bf16x8*)(sm + bufo + rBo[j]);
        asm volatile("s_waitcnt lgkmcnt(0)" ::: "memory");
        __builtin_amdgcn_sched_barrier(0);

        __builtin_amdgcn_s_setprio(1);
#pragma unroll
        for (int i = 0; i < FM; ++i)
#pragma unroll
            for (int j = 0; j < FN; ++j)
                acc[i][j] = __builtin_amdgcn_mfma_f32_16x16x32_bf16(af[i], bq[j], acc[i][j], 0, 0, 0);
        __builtin_amdgcn_s_setprio(0);

        __builtin_amdgcn_s_barrier();          // all waves done reading buf `bufo`
        if (it + 3 < NT) stage(bufo, it + 3);  // restage freed buffer
        bufo = (bufo == 2 * BUFB) ? 0 : bufo + BUFB;
    }

    // ---------------- epilogue ----------------
    const int q4   = q << 2;
    const int colb = n0 + wn * WN + (lane & 15);
    if constexpr (EPI == 0) {
        u16* C = (u16*)Cbase + (size_t)b * sC;
#pragma unroll
        for (int i = 0; i < FM; ++i)
#pragma unroll
            for (int rr = 0; rr < 4; ++rr) {
                const int row = m0 + wm * WM + i * 16 + q4 + rr;
                const float bias = aux1[row];
#pragma unroll
                for (int j = 0; j < FN; ++j)
                    C[(size_t)row * ldC + colb + j * 16] = f2bf(acc[i][j][rr] + bias);
            }
    } else if constexpr (EPI == 3) {
        float* C = (float*)Cbase + (size_t)b * sC;
#pragma unroll
        for (int i = 0; i < FM; ++i)
#pragma unroll
            for (int rr = 0; rr < 4; ++rr) {
                const int row = m0 + wm * WM + i * 16 + q4 + rr;
                const float bias = aux1[row];
#pragma unroll
                for (int j = 0; j < FN; ++j)
                    C[(size_t)row * ldC + colb + j * 16] = acc[i][j][rr] + bias;
            }
    } else if constexpr (EPI == 1) {       // beta partials: [ks][t][64][512]
        float* C = (float*)Cbase + (size_t)blockIdx.y * 98304 + (size_t)t * (64 * HH);
#pragma unroll
        for (int i = 0; i < FM; ++i)
#pragma unroll
            for (int rr = 0; rr < 4; ++rr) {
                const int row = wm * WM + i * 16 + q4 + rr;
#pragma unroll
                for (int j = 0; j < FN; ++j)
                    C[(size_t)row * HH + colb + j * 16] = acc[i][j][rr];
            }
    } else if constexpr (EPI == 2) {       // G5: fused 8-partial beta reduce
        u16* C = (u16*)Cbase;
        const int bb = (t == 0) ? g : ((((t == 1) ? (g - 64) : (g - 96)) << 1) + wm);
        float bet[FN];
#pragma unroll
        for (int j = 0; j < FN; ++j) {
            const int col = colb + j * 16;
            float s = 0.f;
#pragma unroll
            for (int ks = 0; ks < 8; ++ks)
                s += aux1[(size_t)ks * 98304 + (size_t)((t << 6) + bb) * HH + col];
            bet[j] = (s + aux2[t * HH + col]) * (1.f / 3.f);
        }
#pragma unroll
        for (int i = 0; i < FM; ++i)
#pragma unroll
            for (int rr = 0; rr < 4; ++rr) {
                const int rl = wm * WM + i * 16 + q4 + rr;
                const int glob = g5row(t, g, rl);          // b*256+n
#pragma unroll
                for (int j = 0; j < FN; ++j) {
                    const float v = acc[i][j][rr] + bet[j];
                    C[(size_t)glob * ldC + colb + j * 16] = f2bf(fmaxf(v, 0.f));
                }
            }
    } else {                               // EPI == 4: bf16 + bias + fused mu
        u16* C = (u16*)Cbase + (size_t)b * sC;
        float t0[FN], t1[FN];
#pragma unroll
        for (int j = 0; j < FN; ++j) { t0[j] = 0.f; t1[j] = 0.f; }
#pragma unroll
        for (int i = 0; i < FM; ++i)
#pragma unroll
            for (int rr = 0; rr < 4; ++rr) {
                const int row = m0 + wm * WM + i * 16 + q4 + rr;
                const float bias = aux1[row];
#pragma unroll
                for (int j = 0; j < FN; ++j) {
                    const float hv = acc[i][j][rr] + bias;
                    C[(size_t)row * ldC + colb + j * 16] = f2bf(hv);
                    if (wm == 0)            t0[j] += hv;   // rows 0..127   = type A
                    else if (i < FM / 2)    t0[j] += hv;   // rows 128..191 = type B
                    else                    t1[j] += hv;   // rows 192..255 = type C
                }
            }
#pragma unroll
        for (int j = 0; j < FN; ++j) {     // reduce across q-groups (rows)
            t0[j] += __shfl_xor(t0[j], 16, 64);
            t0[j] += __shfl_xor(t0[j], 32, 64);
            t1[j] += __shfl_xor(t1[j], 16, 64);
            t1[j] += __shfl_xor(t1[j], 32, 64);
        }
        if (lane < 16) {
#pragma unroll
            for (int j = 0; j < FN; ++j) {
                const int col = colb + j * 16;             // = s index (f)
                if (wm == 0) {
                    const u16 v = f2bf(t0[j] * (1.f / 128.f));
#pragma unroll
                    for (int tt = 0; tt < 3; ++tt)
                        muOut[((size_t)tt * BB + b) * 3072 + (size_t)d_slotE[0][tt] * 1024 + col] = v;
                } else {
                    const u16 vB = f2bf(t0[j] * (1.f / 64.f));
                    const u16 vC = f2bf(t1[j] * (1.f / 64.f));
#pragma unroll
                    for (int tt = 0; tt < 3; ++tt) {
                        muOut[((size_t)tt * BB + b) * 3072 + (size_t)d_slotE[1][tt] * 1024 + col] = vB;
                        muOut[((size_t)tt * BB + b) * 3072 + (size_t)d_slotE[2][tt] * 1024 + col] = vC;
                    }
                }
            }
        }
    }
}

// ---------------------------------------------------------------------------
extern "C" void kernel_launch(void* const* d_in, const int* in_sizes, int n_in,
                              void* d_out, int out_size, void* d_ws, size_t ws_size,
                              hipStream_t stream) {
    const float* x  = (const float*)d_in[0];
    const float* W1 = (const float*)d_in[1];
    const float* b1 = (const float*)d_in[2];
    const float* Wl = (const float*)d_in[3];
    const float* bl = (const float*)d_in[4];
    const float* Wr = (const float*)d_in[5];
    const float* Wf = (const float*)d_in[6];
    const float* bf = (const float*)d_in[7];
    const float* W2 = (const float*)d_in[8];
    const float* b2 = (const float*)d_in[9];
    float* y = (float*)d_out;

    // workspace layout (u16 elements)
    u16* wsS   = (u16*)d_ws;
    u16* xT    = wsS;                       // [64][1024][256] = 16,777,216
    u16* h     = wsS + 16777216;            // [64][256][1024] = 16,777,216
    u16* r     = wsS + 33554432;            // [64][256][512]  =  8,388,608
    u16* W1T   = wsS + 41943040;            // [256][256]
    u16* W2T   = wsS + 42008576;            // [256][256]
    u16* WfT   = wsS + 42074112;            // [1024][512]
    u16* WsumT = wsS + 42598400;            // [3][512][1024]
    u16* WlTc  = wsS + 44171264;            // [3][512][3072]
    u16* muCat = wsS + 48889856;            // [3][64][3072]
    float* blsum = (float*)(wsS + 49479680);  // [3][512] f32
    // tmp8 ([8][3][64][512] f32 = 3.1MB) lives in xT's region: xT is dead after
    // G1 (its only reader), beta-gemm writes tmp8, G5 reads it, then G6's outT
    // (also aliased to xT) overwrites it. Stream order guarantees safety.
    float* tmp8 = (float*)xT;
    u16* outT = xT;                           // alias: xT dead after G1

    // weight prep (one launch) + x transpose
    prep_weights<<<dim3(6785), 256, 0, stream>>>(W1, W2, Wf, Wl, Wr, bl,
                                                 W1T, W2T, WfT, WlTc, WsumT, blsum);
    transpose_bf16<<<dim3(32, 8, 64), 256, 0, stream>>>(x, xT, 256, 1024);

    // G1: h[b][n][s] = W1T[n][d] . xT[b][s][d] + b1[n], fused mu -> muCat
    gemm2<256, 128, 256, 4, 0><<<dim3(8, 1, 64), 256, 0, stream>>>(
        W1T, xT, h, b1, nullptr, muCat, 262144, 262144, 256, 256, 1024);
    // beta partials: tmp8[ks][t][b][h] = muCat[t][b][kslice] . WlTc[t][h][kslice]
    gemm2<64, 64, 384, 1, 2><<<dim3(8, 8, 3), 256, 0, stream>>>(
        muCat, WlTc, tmp8, nullptr, nullptr, nullptr, 0, 0, 3072, 3072, 512);
    // G5: r[b][n][h] = relu( h[b][n][:] . WsumT[t][h][:] + (sum tmp8 + blsum)/3 )
    gemm2<128, 128, 1024, 2, 1><<<dim3(4, 128, 1), 256, 0, stream>>>(
        h, WsumT, r, tmp8, blsum, nullptr, 0, 0, 1024, 1024, 512);
    // G6: outT[b][f][n] = WfT[f][h] . r[b][n][h] + bf[f]
    gemm2<256, 128, 512, 0, 0><<<dim3(2, 4, 64), 256, 0, stream>>>(
        WfT, r, outT, bf, nullptr, nullptr, 131072, 262144, 512, 512, 256);
    // G7: y[b][d][s] = W2T[d][n] . outT[b][s][n] + b2[d]
    gemm2<256, 128, 256, 3, 0><<<dim3(8, 1, 64), 256, 0, stream>>>(
        W2T, outT, y, b2, nullptr, nullptr, 262144, 262144, 256, 256, 1024);
}